// Round 9
// baseline (203.512 us; speedup 1.0000x reference)
//
#include <hip/hip_runtime.h>
#include <hip/hip_bf16.h>

// DiffAttention on MI355X: bf16 MFMA pipeline, round 18 (= r17 resubmit;
// round 8's bench died on container acquisition, kernel never ran).
// r17 theory: attn per-pair skeleton cost is K-DMA issued ~300cy before the
// barrier that vmcnt(0)-drains it (~700cy exposed) + 16 ds_read_b128/wave/
// pair. r13 (inline K loads) failed on exposed latency; pipelined issue
// (kt+1 loads issued BEFORE kt compute, ~2000cy cover) hides it. Deletes Ks
// LDS (48->32KB), K-DMA, K ds_reads. Noise-proof signature: BANK_CONFLICT
// 2.2M -> ~1.4M. Tripwire: attn >=63us with conflicts down => r14 attn is
// the floor; pivot to GEMM side permanently.
// Workspace layout (bytes):
//   xb   @ 0      8MB   (x bf16, 4096x1024)           [reused later for Oc]
//   Wqb  @ 8M     2MB   Wkb @10M  Wvb @12M  Wob @14M
//   Qb   @16M    8MB   Kb @24M   Vb @32M   (each 4096x1024 bf16; Q pre-scaled)
//   Op   @40M   16MB   (O^T per component head: (B,16,128,S) bf16)
//   Oc   @ 0     8MB   (combined (B,S,1024) bf16, reuses xb region)

typedef unsigned short ushort_t;
typedef short short8 __attribute__((ext_vector_type(8)));
typedef short short4v __attribute__((ext_vector_type(4)));
typedef unsigned short ushort8v __attribute__((ext_vector_type(8)));
typedef unsigned short ushort4v __attribute__((ext_vector_type(4)));
typedef float f32x4 __attribute__((ext_vector_type(4)));
typedef float f32x16 __attribute__((ext_vector_type(16)));
typedef unsigned int uint2v __attribute__((ext_vector_type(2)));
typedef unsigned int uint4v __attribute__((ext_vector_type(4)));

#define SEQ 2048
#define DIMM 1024
#define LAMBDA_INIT 0.7008206670670481f
#define QSCALE 0.18033688011112042f  // 0.125 * log2(e): scores land in log2 domain
#define SBASE 8.0f                   // fixed softmax base (log2 units)

__device__ __forceinline__ unsigned short f2bf(float f) {
  unsigned int u = __float_as_uint(f);
  unsigned int r = u + 0x7fffu + ((u >> 16) & 1u);
  return (unsigned short)(r >> 16);
}
__device__ __forceinline__ float bf2f(unsigned short v) {
  unsigned int u = ((unsigned int)v) << 16;
  return __uint_as_float(u);
}

__device__ __forceinline__ void async16(ushort_t* lds, const ushort_t* g) {
  __builtin_amdgcn_global_load_lds(
      (__attribute__((address_space(1))) void*)(ushort_t*)g,
      (__attribute__((address_space(3))) void*)lds, 16, 0, 0);
}

// ---------------------------------------------------------------------------
// Fused fp32->bf16 convert: x (4M) then Wq/Wk/Wv/Wo (1M each). 8192 blocks.
__global__ void cvt_all_kernel(const float* __restrict__ x,
                               const float* __restrict__ Wq, const float* __restrict__ Wk,
                               const float* __restrict__ Wv, const float* __restrict__ Wo,
                               ushort_t* __restrict__ xb,
                               ushort_t* __restrict__ Wqb, ushort_t* __restrict__ Wkb,
                               ushort_t* __restrict__ Wvb, ushort_t* __restrict__ Wob) {
  int i = (blockIdx.x * 256 + threadIdx.x) * 4;
  const float* src;
  ushort_t* dst;
  int off;
  if (i < 4194304) {
    src = x; dst = xb; off = i;
  } else {
    int j = i - 4194304;
    int w = j >> 20;
    off = j & 1048575;
    src = (w == 0) ? Wq : (w == 1) ? Wk : (w == 2) ? Wv : Wo;
    dst = (w == 0) ? Wqb : (w == 1) ? Wkb : (w == 2) ? Wvb : Wob;
  }
  f32x4 v = *(const f32x4*)(src + off);
  ushort4v o;
  o[0] = f2bf(v[0]); o[1] = f2bf(v[1]); o[2] = f2bf(v[2]); o[3] = f2bf(v[3]);
  *(ushort4v*)(dst + off) = o;
}

// ---------------------------------------------------------------------------
// Fused QKV: C_w[4096,1024] = x * W_w^T, w selected by blockIdx.x>>3.
// Q slice (w==0) pre-scaled by QSCALE. 128x128 tile, BK=64. launch_bounds
// (256,3): 768-block grid fits one residency round (no 2-round tail).
__global__ __launch_bounds__(256, 3) void gemm_qkv_kernel(
    const ushort_t* __restrict__ A,
    const ushort_t* __restrict__ Wq, const ushort_t* __restrict__ Wk,
    const ushort_t* __restrict__ Wv,
    ushort_t* __restrict__ Qo, ushort_t* __restrict__ Ko, ushort_t* __restrict__ Vo) {
  __shared__ __attribute__((aligned(16))) ushort_t As[128 * 64];
  __shared__ __attribute__((aligned(16))) ushort_t Bs[128 * 64];
  const int K = 1024, N = 1024;
  const int w = blockIdx.x >> 3;
  const ushort_t* Bt = (w == 0) ? Wq : (w == 1) ? Wk : Wv;
  ushort_t* C = (w == 0) ? Qo : (w == 1) ? Ko : Vo;
  const float oscale = (w == 0) ? QSCALE : 1.0f;
  const int bn = (blockIdx.x & 7) * 128;
  const int bm = blockIdx.y * 128;

  const int tid = threadIdx.x, lane = tid & 63, wv = tid >> 6;
  const int quad = lane >> 4, m15 = lane & 15;
  const int wm = (wv >> 1) * 64, wn = (wv & 1) * 64;

  f32x4 acc[4][4] = {};
  const int srow = lane >> 3;                        // row within 8-row chunk
  const int sk8 = (lane & 7) ^ ((lane >> 3) & 7);    // logical k8 for this lane's slot

  for (int k0 = 0; k0 < K; k0 += 64) {
#pragma unroll
    for (int cc = 0; cc < 4; ++cc) {
      int ch = wv * 4 + cc;
      async16(&As[ch * 512], A + (size_t)(bm + ch * 8 + srow) * K + k0 + sk8 * 8);
      async16(&Bs[ch * 512], Bt + (size_t)(bn + ch * 8 + srow) * K + k0 + sk8 * 8);
    }
    __syncthreads();
#pragma unroll
    for (int ks = 0; ks < 2; ++ks) {
      short8 af[4], bfr[4];
#pragma unroll
      for (int t = 0; t < 4; ++t) {
        int ra = wm + t * 16 + m15;
        af[t] = *(const short8*)&As[ra * 64 + (((ks * 4 + quad) ^ (ra & 7))) * 8];
        int rb = wn + t * 16 + m15;
        bfr[t] = *(const short8*)&Bs[rb * 64 + (((ks * 4 + quad) ^ (rb & 7))) * 8];
      }
#pragma unroll
      for (int mt = 0; mt < 4; ++mt)
#pragma unroll
        for (int nt = 0; nt < 4; ++nt)
          acc[mt][nt] = __builtin_amdgcn_mfma_f32_16x16x32_bf16(af[mt], bfr[nt], acc[mt][nt], 0, 0, 0);
    }
    __syncthreads();
  }

#pragma unroll
  for (int mt = 0; mt < 4; ++mt)
#pragma unroll
    for (int nt = 0; nt < 4; ++nt) {
      int col = bn + wn + nt * 16 + m15;
#pragma unroll
      for (int r = 0; r < 4; ++r) {
        int row = bm + wm + mt * 16 + quad * 4 + r;
        C[(size_t)row * N + col] = f2bf(acc[mt][nt][r] * oscale);
      }
    }
}

// ---------------------------------------------------------------------------
// O-projection: C[4096,1024] f32 = Oc * Wo^T. 128x64 tiles, BK=64.
// 512 blocks = 2/CU exact (no tail) at (256,2).
__global__ __launch_bounds__(256, 2) void gemm_bt64_kernel(
    const ushort_t* __restrict__ A, const ushort_t* __restrict__ Bt,
    float* __restrict__ C, int M, int N, int K) {
  __shared__ __attribute__((aligned(16))) ushort_t As[128 * 64];
  __shared__ __attribute__((aligned(16))) ushort_t Bs[64 * 64];
  const int tid = threadIdx.x, lane = tid & 63, wv = tid >> 6;
  const int quad = lane >> 4, m15 = lane & 15;
  const int wm = (wv >> 1) * 64, wn = (wv & 1) * 32;
  const int bm = blockIdx.y * 128, bn = blockIdx.x * 64;
  f32x4 acc[4][2] = {};
  const int srow = lane >> 3;
  const int sk8 = (lane & 7) ^ ((lane >> 3) & 7);

  for (int k0 = 0; k0 < K; k0 += 64) {
#pragma unroll
    for (int cc = 0; cc < 4; ++cc) {
      int ch = wv * 4 + cc;
      async16(&As[ch * 512], A + (size_t)(bm + ch * 8 + srow) * K + k0 + sk8 * 8);
    }
#pragma unroll
    for (int cc = 0; cc < 2; ++cc) {
      int ch = wv * 2 + cc;
      async16(&Bs[ch * 512], Bt + (size_t)(bn + ch * 8 + srow) * K + k0 + sk8 * 8);
    }
    __syncthreads();
#pragma unroll
    for (int ks = 0; ks < 2; ++ks) {
      short8 af[4], bfr[2];
#pragma unroll
      for (int t = 0; t < 4; ++t) {
        int ra = wm + t * 16 + m15;
        af[t] = *(const short8*)&As[ra * 64 + (((ks * 4 + quad) ^ (ra & 7))) * 8];
      }
#pragma unroll
      for (int t = 0; t < 2; ++t) {
        int rb = wn + t * 16 + m15;
        bfr[t] = *(const short8*)&Bs[rb * 64 + (((ks * 4 + quad) ^ (rb & 7))) * 8];
      }
#pragma unroll
      for (int mt = 0; mt < 4; ++mt)
#pragma unroll
        for (int nt = 0; nt < 2; ++nt)
          acc[mt][nt] = __builtin_amdgcn_mfma_f32_16x16x32_bf16(af[mt], bfr[nt], acc[mt][nt], 0, 0, 0);
    }
    __syncthreads();
  }
#pragma unroll
  for (int mt = 0; mt < 4; ++mt)
#pragma unroll
    for (int nt = 0; nt < 2; ++nt) {
      int col = bn + wn + nt * 16 + m15;
#pragma unroll
      for (int r = 0; r < 4; ++r) {
        int row = bm + wm + mt * 16 + quad * 4 + r;
        C[(size_t)row * N + col] = acc[mt][nt][r];
      }
    }
}

// ---------------------------------------------------------------------------
// Flash attention, causal, per (b, component head h2, 128-row q-tile).
// CU-balanced heavy-first (pairs on one CU sum to 15). Fixed-base softmax:
// P = exp2(s - SBASE). 32x32x16 MFMAs; swapped QK^T (A=K, B=Q) makes P
// lane-local; PV B-frags via shfl_xor(32)+select (r14 path). K-frags in
// REGISTERS, one-sub-tile-ahead prefetch (issue loads for kt+1 before
// computing kt; ~2000cy compute covers L2 latency). No Ks LDS, no K-DMA,
// no K ds_reads. V staged to LDS as before. LDS = Vt 32KB.
__global__ __launch_bounds__(256, 2) void attn_kernel(
    const ushort_t* __restrict__ Q, const ushort_t* __restrict__ Kg,
    const ushort_t* __restrict__ Vg, ushort_t* __restrict__ Op) {
  __shared__ __attribute__((aligned(16))) ushort_t Vt[2][128 * 64]; // per sub-tile: d x keys

  const int tid = threadIdx.x, lane = tid & 63, wv = tid >> 6;
  const int l31 = lane & 31, hi = lane >> 5;
  const int bid = blockIdx.x;
  const int g = bid >> 5;
  const int qt = (g < 8) ? (15 - g) : (g - 8);   // same-CU pair sums to 15
  const int h2 = bid & 15, b = (bid >> 4) & 1;
  const int qrow0 = qt * 128 + wv * 32;
  const int vcol = (h2 >> 1) * 128;

  // Q fragments resident (B-operand 32x32x16: n=q=l31, k=kstep*16+hi*8+j)
  short8 qf2[4];
#pragma unroll
  for (int kstep = 0; kstep < 4; ++kstep)
    qf2[kstep] = *(const short8*)&Q[(size_t)(b * SEQ + qrow0 + l31) * DIMM +
                                    h2 * 64 + kstep * 16 + hi * 8];

  // K fragment base (A-operand 32x32x16: row=key=kt*64+kb*32+l31,
  // cols kstep*16+hi*8..+7 -- 16B contiguous, layout == memory layout).
  const ushort_t* kbp = Kg + (size_t)(b * SEQ + l31) * DIMM + h2 * 64 + hi * 8;
  const int ktmax = (qrow0 + 31) >> 6;  // last sub-tile this wave touches

  // prologue: prefetch K-frags for sub-tile kt=0 (every wave uses kt=0)
  short8 kfp[2][4];
#pragma unroll
  for (int kb = 0; kb < 2; ++kb)
#pragma unroll
    for (int kstep = 0; kstep < 4; ++kstep)
      kfp[kb][kstep] = *(const short8*)(kbp + (size_t)(kb * 32) * DIMM + kstep * 16);

  // V staging: thread owns 8 dims x 4 keys x 2 sub-tiles; prefetch pair 0
  const int dg = tid & 15;   // dim-chunk (8 dims)
  const int kq = tid >> 4;   // 4-key group (0..15)
  const ushort_t* vb = Vg + (size_t)(b * SEQ) * DIMM + vcol + dg * 8;
  ushort8v vp[2][4];
#pragma unroll
  for (int t = 0; t < 2; ++t)
#pragma unroll
    for (int i = 0; i < 4; ++i)
      vp[t][i] = *(const ushort8v*)(vb + (size_t)(t * 64 + kq * 4 + i) * DIMM);

  f32x16 oacc[4] = {};
  float lsum = 0.f;

  const int npair = qt + 1;   // tiles 0..2qt+1 = qt+1 pairs
  for (int p = 0; p < npair; ++p) {
    // ---- write both Vt sub-tiles from prefetched regs (swizzled b64 writes)
    {
      const int ck = kq >> 1, off4 = (kq & 1) * 4;
#pragma unroll
      for (int t = 0; t < 2; ++t)
#pragma unroll
        for (int j = 0; j < 8; ++j) {
          int d = dg * 8 + j;
          int pp = ck ^ ((d ^ (d >> 3)) & 7);
          uint2v pw;
          pw[0] = (unsigned int)vp[t][0][j] | ((unsigned int)vp[t][1][j] << 16);
          pw[1] = (unsigned int)vp[t][2][j] | ((unsigned int)vp[t][3][j] << 16);
          *(short4v*)&Vt[t][d * 64 + pp * 8 + off4] = __builtin_bit_cast(short4v, pw);
        }
    }
    __syncthreads();
    // ---- prefetch next pair's V (overlaps with compute below)
    if (p + 1 < npair) {
#pragma unroll
      for (int t = 0; t < 2; ++t)
#pragma unroll
        for (int i = 0; i < 4; ++i)
          vp[t][i] = *(const ushort8v*)(vb + (size_t)((p + 1) * 128 + t * 64 + kq * 4 + i) * DIMM);
    }

#pragma unroll
    for (int t = 0; t < 2; ++t) {
      const int kt = 2 * p + t;
      if (kt > ktmax) continue;  // fully masked for this wave
      // ---- consume current K-frags; issue prefetch for kt+1 BEFORE compute
      short8 kfc[2][4];
#pragma unroll
      for (int kb = 0; kb < 2; ++kb)
#pragma unroll
        for (int kstep = 0; kstep < 4; ++kstep)
          kfc[kb][kstep] = kfp[kb][kstep];
      if (kt + 1 <= ktmax) {
        const ushort_t* kn = kbp + (size_t)((kt + 1) * 64) * DIMM;
#pragma unroll
        for (int kb = 0; kb < 2; ++kb)
#pragma unroll
          for (int kstep = 0; kstep < 4; ++kstep)
            kfp[kb][kstep] = *(const short8*)(kn + (size_t)(kb * 32) * DIMM + kstep * 16);
      }
#pragma unroll
      for (int kb = 0; kb < 2; ++kb) {
        // ---- S^T = K Q^T (32x32x16; A=K frags in regs, B=Q resident)
        f32x16 sacc = {};
#pragma unroll
        for (int kstep = 0; kstep < 4; ++kstep)
          sacc = __builtin_amdgcn_mfma_f32_32x32x16_bf16(kfc[kb][kstep], qf2[kstep], sacc, 0, 0, 0);
        if (kt * 64 + 63 > qrow0) {  // diagonal tile only: causal mask
#pragma unroll
          for (int r = 0; r < 16; ++r) {
            int kg = kt * 64 + kb * 32 + (r & 3) + 8 * (r >> 2) + 4 * hi;
            int qg = qrow0 + l31;
            if (kg > qg) sacc[r] = -3.0e38f;
          }
        }
        // ---- P = exp2(S - SBASE); pack reg pairs to bf16x2 words
        unsigned int w[8];
#pragma unroll
        for (int i = 0; i < 8; ++i) {
          float e0 = __builtin_amdgcn_exp2f(sacc[2 * i] - SBASE);
          float e1 = __builtin_amdgcn_exp2f(sacc[2 * i + 1] - SBASE);
          lsum += e0 + e1;
          w[i] = __builtin_amdgcn_perm(__float_as_uint(e1) + 0x8000u,
                                       __float_as_uint(e0) + 0x8000u, 0x07060302u);
        }
        // ---- build PV B-frags: lane needs k=(lane>>5)*8+j per 16-key step;
        // held k = pairbase{0,2,8,10,16,18,24,26}+4*hi -> lane^32 exchange.
        unsigned int sw[8];
#pragma unroll
        for (int i = 0; i < 8; ++i)
          sw[i] = (unsigned int)__shfl_xor((int)w[i], 32);
        uint4v p0, p1;
        p0[0] = hi ? sw[2] : w[0];  p0[1] = hi ? sw[3] : w[1];
        p0[2] = hi ? w[2] : sw[0];  p0[3] = hi ? w[3] : sw[1];
        p1[0] = hi ? sw[6] : w[4];  p1[1] = hi ? sw[7] : w[5];
        p1[2] = hi ? w[6] : sw[4];  p1[3] = hi ? w[7] : sw[5];
        short8 pf0 = __builtin_bit_cast(short8, p0);
        short8 pf1 = __builtin_bit_cast(short8, p1);
        // ---- O^T += V^T P^T (A=V^T frags from LDS, B=P in reg)
#pragma unroll
        for (int db = 0; db < 4; ++db) {
          int d = db * 32 + l31;
          int f = (d ^ (d >> 3)) & 7;
          short8 av0 = *(const short8*)&Vt[t][d * 64 + (((kb * 4 + hi) ^ f)) * 8];
          oacc[db] = __builtin_amdgcn_mfma_f32_32x32x16_bf16(av0, pf0, oacc[db], 0, 0, 0);
          short8 av1 = *(const short8*)&Vt[t][d * 64 + (((kb * 4 + 2 + hi) ^ f)) * 8];
          oacc[db] = __builtin_amdgcn_mfma_f32_32x32x16_bf16(av1, pf1, oacc[db], 0, 0, 0);
        }
      }
    }
    __syncthreads();
  }

  // ---- epilogue: row sum is lane-local + partner half; normalize and store
  float lrow = lsum + __shfl_xor(lsum, 32);
  float li = 1.0f / lrow;
  const int s = qrow0 + l31;
#pragma unroll
  for (int db = 0; db < 4; ++db)
#pragma unroll
    for (int r = 0; r < 16; ++r) {
      int d = db * 32 + (r & 3) + 8 * (r >> 2) + 4 * hi;
      Op[(size_t)((b * 16 + h2) * 128 + d) * SEQ + s] = f2bf(oacc[db][r] * li);
    }
}

// ---------------------------------------------------------------------------
__global__ __launch_bounds__(256) void combine_kernel(
    const ushort_t* __restrict__ Op, const float* __restrict__ lq1,
    const float* __restrict__ lk1, const float* __restrict__ lq2,
    const float* __restrict__ lk2, ushort_t* __restrict__ Oc) {
  const int tid = threadIdx.x;
  const int st = blockIdx.x, h = blockIdx.y, b = blockIdx.z;
  float d1 = 0.f, d2 = 0.f;
  for (int i = 0; i < 64; ++i) { d1 += lq1[i] * lk1[i]; d2 += lq2[i] * lk2[i]; }
  const float lam = __expf(d1) - __expf(d2) + LAMBDA_INIT;

  const int sl = tid & 63, dg = tid >> 6;
  const int s = st * 64 + sl;
  const ushort_t* O1 = Op + (size_t)((b * 16 + 2 * h) * 128 + dg * 32) * SEQ + s;
  const ushort_t* O2 = O1 + (size_t)128 * SEQ;

  float u[32];
  float ssq = 0.f;
#pragma unroll
  for (int i = 0; i < 32; ++i) {
    float a = bf2f(O1[(size_t)i * SEQ]);
    float c = bf2f(O2[(size_t)i * SEQ]);
    float uu = a - lam * c;
    u[i] = uu;
    ssq += uu * uu;
  }
  __shared__ float red[4][64];
  red[dg][sl] = ssq;
  __syncthreads();
  float tot = red[0][sl] + red[1][sl] + red[2][sl] + red[3][sl];
  float scl = rsqrtf(tot * (1.0f / 128.0f) + 1e-5f) * (1.0f - LAMBDA_INIT);

  uint4v ow[4];
#pragma unroll
  for (int w = 0; w < 4; ++w)
#pragma unroll
    for (int j = 0; j < 4; ++j) {
      int i = w * 8 + j * 2;
      ow[w][j] = (unsigned int)f2bf(u[i] * scl) | ((unsigned int)f2bf(u[i + 1] * scl) << 16);
    }
  uint4v* dst = (uint4v*)&Oc[(size_t)(b * SEQ + s) * DIMM + h * 128 + dg * 32];
#pragma unroll
  for (int w = 0; w < 4; ++w) dst[w] = ow[w];
}

// ---------------------------------------------------------------------------
extern "C" void kernel_launch(void* const* d_in, const int* in_sizes, int n_in,
                              void* d_out, int out_size, void* d_ws, size_t ws_size,
                              hipStream_t stream) {
  const float* x   = (const float*)d_in[0];
  const float* Wq  = (const float*)d_in[1];
  const float* Wk  = (const float*)d_in[2];
  const float* Wv  = (const float*)d_in[3];
  const float* Wo  = (const float*)d_in[4];
  const float* lq1 = (const float*)d_in[5];
  const float* lk1 = (const float*)d_in[6];
  const float* lq2 = (const float*)d_in[7];
  const float* lk2 = (const float*)d_in[8];

  char* ws = (char*)d_ws;
  const size_t MB = 1 << 20;
  if (ws_size < 56 * MB) return;

  ushort_t* xb  = (ushort_t*)(ws + 0);
  ushort_t* Wqb = (ushort_t*)(ws + 8 * MB);
  ushort_t* Wkb = (ushort_t*)(ws + 10 * MB);
  ushort_t* Wvb = (ushort_t*)(ws + 12 * MB);
  ushort_t* Wob = (ushort_t*)(ws + 14 * MB);
  ushort_t* Qb  = (ushort_t*)(ws + 16 * MB);
  ushort_t* Kb  = (ushort_t*)(ws + 24 * MB);
  ushort_t* Vb  = (ushort_t*)(ws + 32 * MB);
  ushort_t* Opb = (ushort_t*)(ws + 40 * MB);
  ushort_t* Oc  = (ushort_t*)(ws + 0);   // reuses xb (dead after QKV gemm)

  cvt_all_kernel<<<8192, 256, 0, stream>>>(x, Wq, Wk, Wv, Wo, xb, Wqb, Wkb, Wvb, Wob);

  gemm_qkv_kernel<<<dim3(24, 32), 256, 0, stream>>>(xb, Wqb, Wkb, Wvb, Qb, Kb, Vb);

  attn_kernel<<<512, 256, 0, stream>>>(Qb, Kb, Vb, Opb);

  combine_kernel<<<dim3(32, 8, 2), 256, 0, stream>>>(Opb, lq1, lk1, lq2, lk2, Oc);

  gemm_bt64_kernel<<<dim3(16, 32), 256, 0, stream>>>(Oc, Wob, (float*)d_out, 4096, 1024, 1024);
}

// Round 10
// 197.349 us; speedup vs baseline: 1.0312x; 1.0312x over previous
//
#include <hip/hip_runtime.h>
#include <hip/hip_bf16.h>

// DiffAttention on MI355X: bf16 MFMA pipeline, round 19.
// r17/18 post-mortem: K-in-reg landed (BANK_CONFLICT 2.2M->1.11M, the
// predicted signature) but attn stayed 62.6us = tripwire hit. Seven attn
// variants pinned at 58-63us -> structural floor (2 waves/SIMD dependent
// chain); revert to r14 attn (best measured 57.9) permanently.
// r19 consolidation + two low-risk mechanism-backed levers:
//  (1) T1 bijective XCD swizzle on both GEMMs (768=8x96, 512=8x64): each
//      XCD gets 4 contiguous bm-rows x all col-tiles -> A-panels L2-resident
//      (qkv: 1MB A + 6MB B streamed; bt64: 3MB total, fully L2-fit).
//  (2) T5 s_setprio(1) around attn MFMA clusters (m191 regime: independent
//      blocks per CU, +4-7%; not m190's lockstep-GEMM null).
// Workspace layout (bytes):
//   xb   @ 0      8MB   (x bf16, 4096x1024)           [reused later for Oc]
//   Wqb  @ 8M     2MB   Wkb @10M  Wvb @12M  Wob @14M
//   Qb   @16M    8MB   Kb @24M   Vb @32M   (each 4096x1024 bf16; Q pre-scaled)
//   Op   @40M   16MB   (O^T per component head: (B,16,128,S) bf16)
//   Oc   @ 0     8MB   (combined (B,S,1024) bf16, reuses xb region)

typedef unsigned short ushort_t;
typedef short short8 __attribute__((ext_vector_type(8)));
typedef short short4v __attribute__((ext_vector_type(4)));
typedef unsigned short ushort8v __attribute__((ext_vector_type(8)));
typedef unsigned short ushort4v __attribute__((ext_vector_type(4)));
typedef float f32x4 __attribute__((ext_vector_type(4)));
typedef float f32x16 __attribute__((ext_vector_type(16)));
typedef unsigned int uint2v __attribute__((ext_vector_type(2)));
typedef unsigned int uint4v __attribute__((ext_vector_type(4)));

#define SEQ 2048
#define DIMM 1024
#define LAMBDA_INIT 0.7008206670670481f
#define QSCALE 0.18033688011112042f  // 0.125 * log2(e): scores land in log2 domain
#define SBASE 8.0f                   // fixed softmax base (log2 units)

__device__ __forceinline__ unsigned short f2bf(float f) {
  unsigned int u = __float_as_uint(f);
  unsigned int r = u + 0x7fffu + ((u >> 16) & 1u);
  return (unsigned short)(r >> 16);
}
__device__ __forceinline__ float bf2f(unsigned short v) {
  unsigned int u = ((unsigned int)v) << 16;
  return __uint_as_float(u);
}

__device__ __forceinline__ void async16(ushort_t* lds, const ushort_t* g) {
  __builtin_amdgcn_global_load_lds(
      (__attribute__((address_space(1))) void*)(ushort_t*)g,
      (__attribute__((address_space(3))) void*)lds, 16, 0, 0);
}

// ---------------------------------------------------------------------------
// Fused fp32->bf16 convert: x (4M) then Wq/Wk/Wv/Wo (1M each). 8192 blocks.
__global__ void cvt_all_kernel(const float* __restrict__ x,
                               const float* __restrict__ Wq, const float* __restrict__ Wk,
                               const float* __restrict__ Wv, const float* __restrict__ Wo,
                               ushort_t* __restrict__ xb,
                               ushort_t* __restrict__ Wqb, ushort_t* __restrict__ Wkb,
                               ushort_t* __restrict__ Wvb, ushort_t* __restrict__ Wob) {
  int i = (blockIdx.x * 256 + threadIdx.x) * 4;
  const float* src;
  ushort_t* dst;
  int off;
  if (i < 4194304) {
    src = x; dst = xb; off = i;
  } else {
    int j = i - 4194304;
    int w = j >> 20;
    off = j & 1048575;
    src = (w == 0) ? Wq : (w == 1) ? Wk : (w == 2) ? Wv : Wo;
    dst = (w == 0) ? Wqb : (w == 1) ? Wkb : (w == 2) ? Wvb : Wob;
  }
  f32x4 v = *(const f32x4*)(src + off);
  ushort4v o;
  o[0] = f2bf(v[0]); o[1] = f2bf(v[1]); o[2] = f2bf(v[2]); o[3] = f2bf(v[3]);
  *(ushort4v*)(dst + off) = o;
}

// ---------------------------------------------------------------------------
// Fused QKV: C_w[4096,1024] = x * W_w^T. 128x128 tile, BK=64. launch_bounds
// (256,3): 768-block grid = one residency round. r19: bijective XCD swizzle
// (768 = 8 x 96): XCD k computes 4 contiguous bm-rows x all 24 (w,bn) tiles
// -> A-panels (1MB) L2-resident per XCD.
__global__ __launch_bounds__(256, 3) void gemm_qkv_kernel(
    const ushort_t* __restrict__ A,
    const ushort_t* __restrict__ Wq, const ushort_t* __restrict__ Wk,
    const ushort_t* __restrict__ Wv,
    ushort_t* __restrict__ Qo, ushort_t* __restrict__ Ko, ushort_t* __restrict__ Vo) {
  __shared__ __attribute__((aligned(16))) ushort_t As[128 * 64];
  __shared__ __attribute__((aligned(16))) ushort_t Bs[128 * 64];
  const int K = 1024, N = 1024;
  // XCD swizzle: dispatch id -> tile id (bijective, 768 = 8*96)
  const int lin = blockIdx.y * 24 + blockIdx.x;
  const int swz = (lin & 7) * 96 + (lin >> 3);
  const int sx = swz % 24, sy = swz / 24;
  const int w = sx >> 3;
  const ushort_t* Bt = (w == 0) ? Wq : (w == 1) ? Wk : Wv;
  ushort_t* C = (w == 0) ? Qo : (w == 1) ? Ko : Vo;
  const float oscale = (w == 0) ? QSCALE : 1.0f;
  const int bn = (sx & 7) * 128;
  const int bm = sy * 128;

  const int tid = threadIdx.x, lane = tid & 63, wv = tid >> 6;
  const int quad = lane >> 4, m15 = lane & 15;
  const int wm = (wv >> 1) * 64, wn = (wv & 1) * 64;

  f32x4 acc[4][4] = {};
  const int srow = lane >> 3;                        // row within 8-row chunk
  const int sk8 = (lane & 7) ^ ((lane >> 3) & 7);    // logical k8 for this lane's slot

  for (int k0 = 0; k0 < K; k0 += 64) {
#pragma unroll
    for (int cc = 0; cc < 4; ++cc) {
      int ch = wv * 4 + cc;
      async16(&As[ch * 512], A + (size_t)(bm + ch * 8 + srow) * K + k0 + sk8 * 8);
      async16(&Bs[ch * 512], Bt + (size_t)(bn + ch * 8 + srow) * K + k0 + sk8 * 8);
    }
    __syncthreads();
#pragma unroll
    for (int ks = 0; ks < 2; ++ks) {
      short8 af[4], bfr[4];
#pragma unroll
      for (int t = 0; t < 4; ++t) {
        int ra = wm + t * 16 + m15;
        af[t] = *(const short8*)&As[ra * 64 + (((ks * 4 + quad) ^ (ra & 7))) * 8];
        int rb = wn + t * 16 + m15;
        bfr[t] = *(const short8*)&Bs[rb * 64 + (((ks * 4 + quad) ^ (rb & 7))) * 8];
      }
#pragma unroll
      for (int mt = 0; mt < 4; ++mt)
#pragma unroll
        for (int nt = 0; nt < 4; ++nt)
          acc[mt][nt] = __builtin_amdgcn_mfma_f32_16x16x32_bf16(af[mt], bfr[nt], acc[mt][nt], 0, 0, 0);
    }
    __syncthreads();
  }

#pragma unroll
  for (int mt = 0; mt < 4; ++mt)
#pragma unroll
    for (int nt = 0; nt < 4; ++nt) {
      int col = bn + wn + nt * 16 + m15;
#pragma unroll
      for (int r = 0; r < 4; ++r) {
        int row = bm + wm + mt * 16 + quad * 4 + r;
        C[(size_t)row * N + col] = f2bf(acc[mt][nt][r] * oscale);
      }
    }
}

// ---------------------------------------------------------------------------
// O-projection: C[4096,1024] f32 = Oc * Wo^T. 128x64 tiles, BK=64.
// 512 blocks = 2/CU exact at (256,2). r19: bijective XCD swizzle (512=8*64):
// XCD k gets 4 contiguous bm-rows x 16 bn -> working set 3MB, L2-resident.
__global__ __launch_bounds__(256, 2) void gemm_bt64_kernel(
    const ushort_t* __restrict__ A, const ushort_t* __restrict__ Bt,
    float* __restrict__ C, int M, int N, int K) {
  __shared__ __attribute__((aligned(16))) ushort_t As[128 * 64];
  __shared__ __attribute__((aligned(16))) ushort_t Bs[64 * 64];
  const int tid = threadIdx.x, lane = tid & 63, wv = tid >> 6;
  const int quad = lane >> 4, m15 = lane & 15;
  const int wm = (wv >> 1) * 64, wn = (wv & 1) * 32;
  const int lin = blockIdx.y * 16 + blockIdx.x;
  const int swz = (lin & 7) * 64 + (lin >> 3);
  const int bm = (swz / 16) * 128, bn = (swz % 16) * 64;
  f32x4 acc[4][2] = {};
  const int srow = lane >> 3;
  const int sk8 = (lane & 7) ^ ((lane >> 3) & 7);

  for (int k0 = 0; k0 < K; k0 += 64) {
#pragma unroll
    for (int cc = 0; cc < 4; ++cc) {
      int ch = wv * 4 + cc;
      async16(&As[ch * 512], A + (size_t)(bm + ch * 8 + srow) * K + k0 + sk8 * 8);
    }
#pragma unroll
    for (int cc = 0; cc < 2; ++cc) {
      int ch = wv * 2 + cc;
      async16(&Bs[ch * 512], Bt + (size_t)(bn + ch * 8 + srow) * K + k0 + sk8 * 8);
    }
    __syncthreads();
#pragma unroll
    for (int ks = 0; ks < 2; ++ks) {
      short8 af[4], bfr[2];
#pragma unroll
      for (int t = 0; t < 4; ++t) {
        int ra = wm + t * 16 + m15;
        af[t] = *(const short8*)&As[ra * 64 + (((ks * 4 + quad) ^ (ra & 7))) * 8];
      }
#pragma unroll
      for (int t = 0; t < 2; ++t) {
        int rb = wn + t * 16 + m15;
        bfr[t] = *(const short8*)&Bs[rb * 64 + (((ks * 4 + quad) ^ (rb & 7))) * 8];
      }
#pragma unroll
      for (int mt = 0; mt < 4; ++mt)
#pragma unroll
        for (int nt = 0; nt < 2; ++nt)
          acc[mt][nt] = __builtin_amdgcn_mfma_f32_16x16x32_bf16(af[mt], bfr[nt], acc[mt][nt], 0, 0, 0);
    }
    __syncthreads();
  }
#pragma unroll
  for (int mt = 0; mt < 4; ++mt)
#pragma unroll
    for (int nt = 0; nt < 2; ++nt) {
      int col = bn + wn + nt * 16 + m15;
#pragma unroll
      for (int r = 0; r < 4; ++r) {
        int row = bm + wm + mt * 16 + quad * 4 + r;
        C[(size_t)row * N + col] = acc[mt][nt][r];
      }
    }
}

// ---------------------------------------------------------------------------
// Flash attention, causal, per (b, component head h2, 128-row q-tile).
// CU-balanced heavy-first (pairs on one CU sum to 15). Fixed-base softmax:
// P = exp2(s - SBASE). 32x32x16 MFMAs; swapped QK^T (A=K, B=Q) makes P
// lane-local; PV B-frags via shfl_xor(32)+select. K staged async per pair,
// V via reg transpose. LDS 48KB. [r14 body + T5 setprio around MFMA]
__global__ __launch_bounds__(256, 2) void attn_kernel(
    const ushort_t* __restrict__ Q, const ushort_t* __restrict__ Kg,
    const ushort_t* __restrict__ Vg, ushort_t* __restrict__ Op) {
  __shared__ __attribute__((aligned(16))) ushort_t Ks[128 * 64];    // 128 keys x 64d, slot = c ^ (key&7)
  __shared__ __attribute__((aligned(16))) ushort_t Vt[2][128 * 64]; // per sub-tile: d x keys

  const int tid = threadIdx.x, lane = tid & 63, wv = tid >> 6;
  const int l31 = lane & 31, hi = lane >> 5;
  const int bid = blockIdx.x;
  const int g = bid >> 5;
  const int qt = (g < 8) ? (15 - g) : (g - 8);   // same-CU pair sums to 15
  const int h2 = bid & 15, b = (bid >> 4) & 1;
  const int qrow0 = qt * 128 + wv * 32;
  const int vcol = (h2 >> 1) * 128;

  // Q fragments resident (B-operand 32x32x16: n=q=l31, k=kstep*16+hi*8+j)
  short8 qf2[4];
#pragma unroll
  for (int kstep = 0; kstep < 4; ++kstep)
    qf2[kstep] = *(const short8*)&Q[(size_t)(b * SEQ + qrow0 + l31) * DIMM +
                                    h2 * 64 + kstep * 16 + hi * 8];

  // V staging: thread owns 8 dims x 4 keys x 2 sub-tiles; prefetch pair 0
  const int dg = tid & 15;   // dim-chunk (8 dims)
  const int kq = tid >> 4;   // 4-key group (0..15)
  const ushort_t* vb = Vg + (size_t)(b * SEQ) * DIMM + vcol + dg * 8;
  ushort8v vp[2][4];
#pragma unroll
  for (int t = 0; t < 2; ++t)
#pragma unroll
    for (int i = 0; i < 4; ++i)
      vp[t][i] = *(const ushort8v*)(vb + (size_t)(t * 64 + kq * 4 + i) * DIMM);

  f32x16 oacc[4] = {};
  float lsum = 0.f;

  const int npair = qt + 1;   // tiles 0..2qt+1 = qt+1 pairs
  for (int p = 0; p < npair; ++p) {
    // ---- stage K pair (async -> LDS; 16 chunks of 8 keys)
    {
      int c = (lane & 7) ^ ((lane >> 3) & 7);
#pragma unroll
      for (int cc = 0; cc < 4; ++cc) {
        int ch = wv * 4 + cc;
        const ushort_t* gk = Kg + (size_t)(b * SEQ + p * 128 + ch * 8 + (lane >> 3)) * DIMM +
                             h2 * 64 + c * 8;
        async16(&Ks[ch * 512], gk);
      }
    }
    // ---- write both Vt sub-tiles from prefetched regs (swizzled b64 writes)
    {
      const int ck = kq >> 1, off4 = (kq & 1) * 4;
#pragma unroll
      for (int t = 0; t < 2; ++t)
#pragma unroll
        for (int j = 0; j < 8; ++j) {
          int d = dg * 8 + j;
          int pp = ck ^ ((d ^ (d >> 3)) & 7);
          uint2v pw;
          pw[0] = (unsigned int)vp[t][0][j] | ((unsigned int)vp[t][1][j] << 16);
          pw[1] = (unsigned int)vp[t][2][j] | ((unsigned int)vp[t][3][j] << 16);
          *(short4v*)&Vt[t][d * 64 + pp * 8 + off4] = __builtin_bit_cast(short4v, pw);
        }
    }
    __syncthreads();
    // ---- prefetch next pair's V (overlaps with compute below)
    if (p + 1 < npair) {
#pragma unroll
      for (int t = 0; t < 2; ++t)
#pragma unroll
        for (int i = 0; i < 4; ++i)
          vp[t][i] = *(const ushort8v*)(vb + (size_t)((p + 1) * 128 + t * 64 + kq * 4 + i) * DIMM);
    }

#pragma unroll
    for (int t = 0; t < 2; ++t) {
      const int kt = 2 * p + t;
      if (kt * 64 > qrow0 + 31) continue;  // fully masked for this wave
#pragma unroll
      for (int kb = 0; kb < 2; ++kb) {
        // ---- S^T = K Q^T (32x32x16; A=K frags from LDS, B=Q resident)
        f32x16 sacc = {};
        __builtin_amdgcn_s_setprio(1);
#pragma unroll
        for (int kstep = 0; kstep < 4; ++kstep) {
          int row = t * 64 + kb * 32 + l31;
          short8 kf = *(const short8*)&Ks[row * 64 + (((kstep * 2 + hi) ^ (row & 7))) * 8];
          sacc = __builtin_amdgcn_mfma_f32_32x32x16_bf16(kf, qf2[kstep], sacc, 0, 0, 0);
        }
        __builtin_amdgcn_s_setprio(0);
        if (kt * 64 + 63 > qrow0) {  // diagonal tile only: causal mask
#pragma unroll
          for (int r = 0; r < 16; ++r) {
            int kg = kt * 64 + kb * 32 + (r & 3) + 8 * (r >> 2) + 4 * hi;
            int qg = qrow0 + l31;
            if (kg > qg) sacc[r] = -3.0e38f;
          }
        }
        // ---- P = exp2(S - SBASE); pack reg pairs to bf16x2 words
        unsigned int w[8];
#pragma unroll
        for (int i = 0; i < 8; ++i) {
          float e0 = __builtin_amdgcn_exp2f(sacc[2 * i] - SBASE);
          float e1 = __builtin_amdgcn_exp2f(sacc[2 * i + 1] - SBASE);
          lsum += e0 + e1;
          w[i] = __builtin_amdgcn_perm(__float_as_uint(e1) + 0x8000u,
                                       __float_as_uint(e0) + 0x8000u, 0x07060302u);
        }
        // ---- build PV B-frags: lane needs k=(lane>>5)*8+j per 16-key step;
        // held k = pairbase{0,2,8,10,16,18,24,26}+4*hi -> lane^32 exchange.
        unsigned int sw[8];
#pragma unroll
        for (int i = 0; i < 8; ++i)
          sw[i] = (unsigned int)__shfl_xor((int)w[i], 32);
        uint4v p0, p1;
        p0[0] = hi ? sw[2] : w[0];  p0[1] = hi ? sw[3] : w[1];
        p0[2] = hi ? w[2] : sw[0];  p0[3] = hi ? w[3] : sw[1];
        p1[0] = hi ? sw[6] : w[4];  p1[1] = hi ? sw[7] : w[5];
        p1[2] = hi ? w[6] : sw[4];  p1[3] = hi ? w[7] : sw[5];
        short8 pf0 = __builtin_bit_cast(short8, p0);
        short8 pf1 = __builtin_bit_cast(short8, p1);
        // ---- O^T += V^T P^T (A=V^T frags from LDS, B=P in reg)
        __builtin_amdgcn_s_setprio(1);
#pragma unroll
        for (int db = 0; db < 4; ++db) {
          int d = db * 32 + l31;
          int f = (d ^ (d >> 3)) & 7;
          short8 av0 = *(const short8*)&Vt[t][d * 64 + (((kb * 4 + hi) ^ f)) * 8];
          oacc[db] = __builtin_amdgcn_mfma_f32_32x32x16_bf16(av0, pf0, oacc[db], 0, 0, 0);
          short8 av1 = *(const short8*)&Vt[t][d * 64 + (((kb * 4 + 2 + hi) ^ f)) * 8];
          oacc[db] = __builtin_amdgcn_mfma_f32_32x32x16_bf16(av1, pf1, oacc[db], 0, 0, 0);
        }
        __builtin_amdgcn_s_setprio(0);
      }
    }
    __syncthreads();
  }

  // ---- epilogue: row sum is lane-local + partner half; normalize and store
  float lrow = lsum + __shfl_xor(lsum, 32);
  float li = 1.0f / lrow;
  const int s = qrow0 + l31;
#pragma unroll
  for (int db = 0; db < 4; ++db)
#pragma unroll
    for (int r = 0; r < 16; ++r) {
      int d = db * 32 + (r & 3) + 8 * (r >> 2) + 4 * hi;
      Op[(size_t)((b * 16 + h2) * 128 + d) * SEQ + s] = f2bf(oacc[db][r] * li);
    }
}

// ---------------------------------------------------------------------------
__global__ __launch_bounds__(256) void combine_kernel(
    const ushort_t* __restrict__ Op, const float* __restrict__ lq1,
    const float* __restrict__ lk1, const float* __restrict__ lq2,
    const float* __restrict__ lk2, ushort_t* __restrict__ Oc) {
  const int tid = threadIdx.x;
  const int st = blockIdx.x, h = blockIdx.y, b = blockIdx.z;
  float d1 = 0.f, d2 = 0.f;
  for (int i = 0; i < 64; ++i) { d1 += lq1[i] * lk1[i]; d2 += lq2[i] * lk2[i]; }
  const float lam = __expf(d1) - __expf(d2) + LAMBDA_INIT;

  const int sl = tid & 63, dg = tid >> 6;
  const int s = st * 64 + sl;
  const ushort_t* O1 = Op + (size_t)((b * 16 + 2 * h) * 128 + dg * 32) * SEQ + s;
  const ushort_t* O2 = O1 + (size_t)128 * SEQ;

  float u[32];
  float ssq = 0.f;
#pragma unroll
  for (int i = 0; i < 32; ++i) {
    float a = bf2f(O1[(size_t)i * SEQ]);
    float c = bf2f(O2[(size_t)i * SEQ]);
    float uu = a - lam * c;
    u[i] = uu;
    ssq += uu * uu;
  }
  __shared__ float red[4][64];
  red[dg][sl] = ssq;
  __syncthreads();
  float tot = red[0][sl] + red[1][sl] + red[2][sl] + red[3][sl];
  float scl = rsqrtf(tot * (1.0f / 128.0f) + 1e-5f) * (1.0f - LAMBDA_INIT);

  uint4v ow[4];
#pragma unroll
  for (int w = 0; w < 4; ++w)
#pragma unroll
    for (int j = 0; j < 4; ++j) {
      int i = w * 8 + j * 2;
      ow[w][j] = (unsigned int)f2bf(u[i] * scl) | ((unsigned int)f2bf(u[i + 1] * scl) << 16);
    }
  uint4v* dst = (uint4v*)&Oc[(size_t)(b * SEQ + s) * DIMM + h * 128 + dg * 32];
#pragma unroll
  for (int w = 0; w < 4; ++w) dst[w] = ow[w];
}

// ---------------------------------------------------------------------------
extern "C" void kernel_launch(void* const* d_in, const int* in_sizes, int n_in,
                              void* d_out, int out_size, void* d_ws, size_t ws_size,
                              hipStream_t stream) {
  const float* x   = (const float*)d_in[0];
  const float* Wq  = (const float*)d_in[1];
  const float* Wk  = (const float*)d_in[2];
  const float* Wv  = (const float*)d_in[3];
  const float* Wo  = (const float*)d_in[4];
  const float* lq1 = (const float*)d_in[5];
  const float* lk1 = (const float*)d_in[6];
  const float* lq2 = (const float*)d_in[7];
  const float* lk2 = (const float*)d_in[8];

  char* ws = (char*)d_ws;
  const size_t MB = 1 << 20;
  if (ws_size < 56 * MB) return;

  ushort_t* xb  = (ushort_t*)(ws + 0);
  ushort_t* Wqb = (ushort_t*)(ws + 8 * MB);
  ushort_t* Wkb = (ushort_t*)(ws + 10 * MB);
  ushort_t* Wvb = (ushort_t*)(ws + 12 * MB);
  ushort_t* Wob = (ushort_t*)(ws + 14 * MB);
  ushort_t* Qb  = (ushort_t*)(ws + 16 * MB);
  ushort_t* Kb  = (ushort_t*)(ws + 24 * MB);
  ushort_t* Vb  = (ushort_t*)(ws + 32 * MB);
  ushort_t* Opb = (ushort_t*)(ws + 40 * MB);
  ushort_t* Oc  = (ushort_t*)(ws + 0);   // reuses xb (dead after QKV gemm)

  cvt_all_kernel<<<8192, 256, 0, stream>>>(x, Wq, Wk, Wv, Wo, xb, Wqb, Wkb, Wvb, Wob);

  gemm_qkv_kernel<<<dim3(24, 32), 256, 0, stream>>>(xb, Wqb, Wkb, Wvb, Qb, Kb, Vb);

  attn_kernel<<<512, 256, 0, stream>>>(Qb, Kb, Vb, Opb);

  combine_kernel<<<dim3(32, 8, 2), 256, 0, stream>>>(Opb, lq1, lk1, lq2, lk2, Oc);

  gemm_bt64_kernel<<<dim3(16, 32), 256, 0, stream>>>(Oc, Wob, (float*)d_out, 4096, 1024, 1024);
}

// Round 11
// 194.430 us; speedup vs baseline: 1.0467x; 1.0150x over previous
//
#include <hip/hip_runtime.h>
#include <hip/hip_bf16.h>

// DiffAttention on MI355X: bf16 MFMA pipeline, round 20 (consolidation).
// r19 post-mortem: total 197.3 (best), split attn 67.3 (tripwire: setprio
// neutral-to-harmful -- two co-resident MFMA-heavy attn blocks starve each
// other; m190-null regime, not m191) / rest ~130 (T1 XCD swizzles on GEMMs
// = real ~-10us gain; keep). r20: attn reverted to byte-exact r14 body
// (best measured 57.9us, structural floor across 7 variants); swizzles kept.
// Workspace layout (bytes):
//   xb   @ 0      8MB   (x bf16, 4096x1024)           [reused later for Oc]
//   Wqb  @ 8M     2MB   Wkb @10M  Wvb @12M  Wob @14M
//   Qb   @16M    8MB   Kb @24M   Vb @32M   (each 4096x1024 bf16; Q pre-scaled)
//   Op   @40M   16MB   (O^T per component head: (B,16,128,S) bf16)
//   Oc   @ 0     8MB   (combined (B,S,1024) bf16, reuses xb region)

typedef unsigned short ushort_t;
typedef short short8 __attribute__((ext_vector_type(8)));
typedef short short4v __attribute__((ext_vector_type(4)));
typedef unsigned short ushort8v __attribute__((ext_vector_type(8)));
typedef unsigned short ushort4v __attribute__((ext_vector_type(4)));
typedef float f32x4 __attribute__((ext_vector_type(4)));
typedef float f32x16 __attribute__((ext_vector_type(16)));
typedef unsigned int uint2v __attribute__((ext_vector_type(2)));
typedef unsigned int uint4v __attribute__((ext_vector_type(4)));

#define SEQ 2048
#define DIMM 1024
#define LAMBDA_INIT 0.7008206670670481f
#define QSCALE 0.18033688011112042f  // 0.125 * log2(e): scores land in log2 domain
#define SBASE 8.0f                   // fixed softmax base (log2 units)

__device__ __forceinline__ unsigned short f2bf(float f) {
  unsigned int u = __float_as_uint(f);
  unsigned int r = u + 0x7fffu + ((u >> 16) & 1u);
  return (unsigned short)(r >> 16);
}
__device__ __forceinline__ float bf2f(unsigned short v) {
  unsigned int u = ((unsigned int)v) << 16;
  return __uint_as_float(u);
}

__device__ __forceinline__ void async16(ushort_t* lds, const ushort_t* g) {
  __builtin_amdgcn_global_load_lds(
      (__attribute__((address_space(1))) void*)(ushort_t*)g,
      (__attribute__((address_space(3))) void*)lds, 16, 0, 0);
}

// ---------------------------------------------------------------------------
// Fused fp32->bf16 convert: x (4M) then Wq/Wk/Wv/Wo (1M each). 8192 blocks.
__global__ void cvt_all_kernel(const float* __restrict__ x,
                               const float* __restrict__ Wq, const float* __restrict__ Wk,
                               const float* __restrict__ Wv, const float* __restrict__ Wo,
                               ushort_t* __restrict__ xb,
                               ushort_t* __restrict__ Wqb, ushort_t* __restrict__ Wkb,
                               ushort_t* __restrict__ Wvb, ushort_t* __restrict__ Wob) {
  int i = (blockIdx.x * 256 + threadIdx.x) * 4;
  const float* src;
  ushort_t* dst;
  int off;
  if (i < 4194304) {
    src = x; dst = xb; off = i;
  } else {
    int j = i - 4194304;
    int w = j >> 20;
    off = j & 1048575;
    src = (w == 0) ? Wq : (w == 1) ? Wk : (w == 2) ? Wv : Wo;
    dst = (w == 0) ? Wqb : (w == 1) ? Wkb : (w == 2) ? Wvb : Wob;
  }
  f32x4 v = *(const f32x4*)(src + off);
  ushort4v o;
  o[0] = f2bf(v[0]); o[1] = f2bf(v[1]); o[2] = f2bf(v[2]); o[3] = f2bf(v[3]);
  *(ushort4v*)(dst + off) = o;
}

// ---------------------------------------------------------------------------
// Fused QKV: C_w[4096,1024] = x * W_w^T. 128x128 tile, BK=64. launch_bounds
// (256,3): 768-block grid = one residency round. Bijective XCD swizzle
// (768 = 8 x 96): XCD k computes 4 contiguous bm-rows x all 24 (w,bn) tiles
// -> A-panels (1MB) L2-resident per XCD.  [kept from r19: real gain]
__global__ __launch_bounds__(256, 3) void gemm_qkv_kernel(
    const ushort_t* __restrict__ A,
    const ushort_t* __restrict__ Wq, const ushort_t* __restrict__ Wk,
    const ushort_t* __restrict__ Wv,
    ushort_t* __restrict__ Qo, ushort_t* __restrict__ Ko, ushort_t* __restrict__ Vo) {
  __shared__ __attribute__((aligned(16))) ushort_t As[128 * 64];
  __shared__ __attribute__((aligned(16))) ushort_t Bs[128 * 64];
  const int K = 1024, N = 1024;
  // XCD swizzle: dispatch id -> tile id (bijective, 768 = 8*96)
  const int lin = blockIdx.y * 24 + blockIdx.x;
  const int swz = (lin & 7) * 96 + (lin >> 3);
  const int sx = swz % 24, sy = swz / 24;
  const int w = sx >> 3;
  const ushort_t* Bt = (w == 0) ? Wq : (w == 1) ? Wk : Wv;
  ushort_t* C = (w == 0) ? Qo : (w == 1) ? Ko : Vo;
  const float oscale = (w == 0) ? QSCALE : 1.0f;
  const int bn = (sx & 7) * 128;
  const int bm = sy * 128;

  const int tid = threadIdx.x, lane = tid & 63, wv = tid >> 6;
  const int quad = lane >> 4, m15 = lane & 15;
  const int wm = (wv >> 1) * 64, wn = (wv & 1) * 64;

  f32x4 acc[4][4] = {};
  const int srow = lane >> 3;                        // row within 8-row chunk
  const int sk8 = (lane & 7) ^ ((lane >> 3) & 7);    // logical k8 for this lane's slot

  for (int k0 = 0; k0 < K; k0 += 64) {
#pragma unroll
    for (int cc = 0; cc < 4; ++cc) {
      int ch = wv * 4 + cc;
      async16(&As[ch * 512], A + (size_t)(bm + ch * 8 + srow) * K + k0 + sk8 * 8);
      async16(&Bs[ch * 512], Bt + (size_t)(bn + ch * 8 + srow) * K + k0 + sk8 * 8);
    }
    __syncthreads();
#pragma unroll
    for (int ks = 0; ks < 2; ++ks) {
      short8 af[4], bfr[4];
#pragma unroll
      for (int t = 0; t < 4; ++t) {
        int ra = wm + t * 16 + m15;
        af[t] = *(const short8*)&As[ra * 64 + (((ks * 4 + quad) ^ (ra & 7))) * 8];
        int rb = wn + t * 16 + m15;
        bfr[t] = *(const short8*)&Bs[rb * 64 + (((ks * 4 + quad) ^ (rb & 7))) * 8];
      }
#pragma unroll
      for (int mt = 0; mt < 4; ++mt)
#pragma unroll
        for (int nt = 0; nt < 4; ++nt)
          acc[mt][nt] = __builtin_amdgcn_mfma_f32_16x16x32_bf16(af[mt], bfr[nt], acc[mt][nt], 0, 0, 0);
    }
    __syncthreads();
  }

#pragma unroll
  for (int mt = 0; mt < 4; ++mt)
#pragma unroll
    for (int nt = 0; nt < 4; ++nt) {
      int col = bn + wn + nt * 16 + m15;
#pragma unroll
      for (int r = 0; r < 4; ++r) {
        int row = bm + wm + mt * 16 + quad * 4 + r;
        C[(size_t)row * N + col] = f2bf(acc[mt][nt][r] * oscale);
      }
    }
}

// ---------------------------------------------------------------------------
// O-projection: C[4096,1024] f32 = Oc * Wo^T. 128x64 tiles, BK=64.
// 512 blocks = 2/CU exact at (256,2). Bijective XCD swizzle (512=8*64):
// XCD k gets 4 contiguous bm-rows x 16 bn -> working set 3MB, L2-resident.
__global__ __launch_bounds__(256, 2) void gemm_bt64_kernel(
    const ushort_t* __restrict__ A, const ushort_t* __restrict__ Bt,
    float* __restrict__ C, int M, int N, int K) {
  __shared__ __attribute__((aligned(16))) ushort_t As[128 * 64];
  __shared__ __attribute__((aligned(16))) ushort_t Bs[64 * 64];
  const int tid = threadIdx.x, lane = tid & 63, wv = tid >> 6;
  const int quad = lane >> 4, m15 = lane & 15;
  const int wm = (wv >> 1) * 64, wn = (wv & 1) * 32;
  const int lin = blockIdx.y * 16 + blockIdx.x;
  const int swz = (lin & 7) * 64 + (lin >> 3);
  const int bm = (swz / 16) * 128, bn = (swz % 16) * 64;
  f32x4 acc[4][2] = {};
  const int srow = lane >> 3;
  const int sk8 = (lane & 7) ^ ((lane >> 3) & 7);

  for (int k0 = 0; k0 < K; k0 += 64) {
#pragma unroll
    for (int cc = 0; cc < 4; ++cc) {
      int ch = wv * 4 + cc;
      async16(&As[ch * 512], A + (size_t)(bm + ch * 8 + srow) * K + k0 + sk8 * 8);
    }
#pragma unroll
    for (int cc = 0; cc < 2; ++cc) {
      int ch = wv * 2 + cc;
      async16(&Bs[ch * 512], Bt + (size_t)(bn + ch * 8 + srow) * K + k0 + sk8 * 8);
    }
    __syncthreads();
#pragma unroll
    for (int ks = 0; ks < 2; ++ks) {
      short8 af[4], bfr[2];
#pragma unroll
      for (int t = 0; t < 4; ++t) {
        int ra = wm + t * 16 + m15;
        af[t] = *(const short8*)&As[ra * 64 + (((ks * 4 + quad) ^ (ra & 7))) * 8];
      }
#pragma unroll
      for (int t = 0; t < 2; ++t) {
        int rb = wn + t * 16 + m15;
        bfr[t] = *(const short8*)&Bs[rb * 64 + (((ks * 4 + quad) ^ (rb & 7))) * 8];
      }
#pragma unroll
      for (int mt = 0; mt < 4; ++mt)
#pragma unroll
        for (int nt = 0; nt < 2; ++nt)
          acc[mt][nt] = __builtin_amdgcn_mfma_f32_16x16x32_bf16(af[mt], bfr[nt], acc[mt][nt], 0, 0, 0);
    }
    __syncthreads();
  }
#pragma unroll
  for (int mt = 0; mt < 4; ++mt)
#pragma unroll
    for (int nt = 0; nt < 2; ++nt) {
      int col = bn + wn + nt * 16 + m15;
#pragma unroll
      for (int r = 0; r < 4; ++r) {
        int row = bm + wm + mt * 16 + quad * 4 + r;
        C[(size_t)row * N + col] = acc[mt][nt][r];
      }
    }
}

// ---------------------------------------------------------------------------
// Flash attention, causal, per (b, component head h2, 128-row q-tile).
// CU-balanced heavy-first (pairs on one CU sum to 15). Fixed-base softmax:
// P = exp2(s - SBASE). 32x32x16 MFMAs; swapped QK^T (A=K, B=Q) makes P
// lane-local (q=lane&31) -- PV B-frags via shfl_xor(32)+select, no P LDS
// round-trip. K staged async per pair, V via reg transpose. LDS 48KB.
// [r14 body, byte-exact -- best measured 57.9us; setprio removed per
//  r19 tripwire (co-resident MFMA-heavy blocks starve each other)]
__global__ __launch_bounds__(256, 2) void attn_kernel(
    const ushort_t* __restrict__ Q, const ushort_t* __restrict__ Kg,
    const ushort_t* __restrict__ Vg, ushort_t* __restrict__ Op) {
  __shared__ __attribute__((aligned(16))) ushort_t Ks[128 * 64];    // 128 keys x 64d, slot = c ^ (key&7)
  __shared__ __attribute__((aligned(16))) ushort_t Vt[2][128 * 64]; // per sub-tile: d x keys

  const int tid = threadIdx.x, lane = tid & 63, wv = tid >> 6;
  const int l31 = lane & 31, hi = lane >> 5;
  const int bid = blockIdx.x;
  const int g = bid >> 5;
  const int qt = (g < 8) ? (15 - g) : (g - 8);   // same-CU pair sums to 15
  const int h2 = bid & 15, b = (bid >> 4) & 1;
  const int qrow0 = qt * 128 + wv * 32;
  const int vcol = (h2 >> 1) * 128;

  // Q fragments resident (B-operand 32x32x16: n=q=l31, k=kstep*16+hi*8+j)
  short8 qf2[4];
#pragma unroll
  for (int kstep = 0; kstep < 4; ++kstep)
    qf2[kstep] = *(const short8*)&Q[(size_t)(b * SEQ + qrow0 + l31) * DIMM +
                                    h2 * 64 + kstep * 16 + hi * 8];

  // V staging: thread owns 8 dims x 4 keys x 2 sub-tiles; prefetch pair 0
  const int dg = tid & 15;   // dim-chunk (8 dims)
  const int kq = tid >> 4;   // 4-key group (0..15)
  const ushort_t* vb = Vg + (size_t)(b * SEQ) * DIMM + vcol + dg * 8;
  ushort8v vp[2][4];
#pragma unroll
  for (int t = 0; t < 2; ++t)
#pragma unroll
    for (int i = 0; i < 4; ++i)
      vp[t][i] = *(const ushort8v*)(vb + (size_t)(t * 64 + kq * 4 + i) * DIMM);

  f32x16 oacc[4] = {};
  float lsum = 0.f;

  const int npair = qt + 1;   // tiles 0..2qt+1 = qt+1 pairs
  for (int p = 0; p < npair; ++p) {
    // ---- stage K pair (async -> LDS; 16 chunks of 8 keys)
    {
      int c = (lane & 7) ^ ((lane >> 3) & 7);
#pragma unroll
      for (int cc = 0; cc < 4; ++cc) {
        int ch = wv * 4 + cc;
        const ushort_t* gk = Kg + (size_t)(b * SEQ + p * 128 + ch * 8 + (lane >> 3)) * DIMM +
                             h2 * 64 + c * 8;
        async16(&Ks[ch * 512], gk);
      }
    }
    // ---- write both Vt sub-tiles from prefetched regs (swizzled b64 writes)
    {
      const int ck = kq >> 1, off4 = (kq & 1) * 4;
#pragma unroll
      for (int t = 0; t < 2; ++t)
#pragma unroll
        for (int j = 0; j < 8; ++j) {
          int d = dg * 8 + j;
          int pp = ck ^ ((d ^ (d >> 3)) & 7);
          uint2v pw;
          pw[0] = (unsigned int)vp[t][0][j] | ((unsigned int)vp[t][1][j] << 16);
          pw[1] = (unsigned int)vp[t][2][j] | ((unsigned int)vp[t][3][j] << 16);
          *(short4v*)&Vt[t][d * 64 + pp * 8 + off4] = __builtin_bit_cast(short4v, pw);
        }
    }
    __syncthreads();
    // ---- prefetch next pair's V (overlaps with compute below)
    if (p + 1 < npair) {
#pragma unroll
      for (int t = 0; t < 2; ++t)
#pragma unroll
        for (int i = 0; i < 4; ++i)
          vp[t][i] = *(const ushort8v*)(vb + (size_t)((p + 1) * 128 + t * 64 + kq * 4 + i) * DIMM);
    }

#pragma unroll
    for (int t = 0; t < 2; ++t) {
      const int kt = 2 * p + t;
      if (kt * 64 > qrow0 + 31) continue;  // fully masked for this wave
#pragma unroll
      for (int kb = 0; kb < 2; ++kb) {
        // ---- S^T = K Q^T (32x32x16; A=K frags from LDS, B=Q resident)
        f32x16 sacc = {};
#pragma unroll
        for (int kstep = 0; kstep < 4; ++kstep) {
          int row = t * 64 + kb * 32 + l31;
          short8 kf = *(const short8*)&Ks[row * 64 + (((kstep * 2 + hi) ^ (row & 7))) * 8];
          sacc = __builtin_amdgcn_mfma_f32_32x32x16_bf16(kf, qf2[kstep], sacc, 0, 0, 0);
        }
        if (kt * 64 + 63 > qrow0) {  // diagonal tile only: causal mask
#pragma unroll
          for (int r = 0; r < 16; ++r) {
            int kg = kt * 64 + kb * 32 + (r & 3) + 8 * (r >> 2) + 4 * hi;
            int qg = qrow0 + l31;
            if (kg > qg) sacc[r] = -3.0e38f;
          }
        }
        // ---- P = exp2(S - SBASE); pack reg pairs to bf16x2 words
        unsigned int w[8];
#pragma unroll
        for (int i = 0; i < 8; ++i) {
          float e0 = __builtin_amdgcn_exp2f(sacc[2 * i] - SBASE);
          float e1 = __builtin_amdgcn_exp2f(sacc[2 * i + 1] - SBASE);
          lsum += e0 + e1;
          w[i] = __builtin_amdgcn_perm(__float_as_uint(e1) + 0x8000u,
                                       __float_as_uint(e0) + 0x8000u, 0x07060302u);
        }
        // ---- build PV B-frags: lane needs k=(lane>>5)*8+j per 16-key step;
        // held k = pairbase{0,2,8,10,16,18,24,26}+4*hi -> lane^32 exchange.
        unsigned int sw[8];
#pragma unroll
        for (int i = 0; i < 8; ++i)
          sw[i] = (unsigned int)__shfl_xor((int)w[i], 32);
        uint4v p0, p1;
        p0[0] = hi ? sw[2] : w[0];  p0[1] = hi ? sw[3] : w[1];
        p0[2] = hi ? w[2] : sw[0];  p0[3] = hi ? w[3] : sw[1];
        p1[0] = hi ? sw[6] : w[4];  p1[1] = hi ? sw[7] : w[5];
        p1[2] = hi ? w[6] : sw[4];  p1[3] = hi ? w[7] : sw[5];
        short8 pf0 = __builtin_bit_cast(short8, p0);
        short8 pf1 = __builtin_bit_cast(short8, p1);
        // ---- O^T += V^T P^T (A=V^T frags from LDS, B=P in reg)
#pragma unroll
        for (int db = 0; db < 4; ++db) {
          int d = db * 32 + l31;
          int f = (d ^ (d >> 3)) & 7;
          short8 av0 = *(const short8*)&Vt[t][d * 64 + (((kb * 4 + hi) ^ f)) * 8];
          oacc[db] = __builtin_amdgcn_mfma_f32_32x32x16_bf16(av0, pf0, oacc[db], 0, 0, 0);
          short8 av1 = *(const short8*)&Vt[t][d * 64 + (((kb * 4 + 2 + hi) ^ f)) * 8];
          oacc[db] = __builtin_amdgcn_mfma_f32_32x32x16_bf16(av1, pf1, oacc[db], 0, 0, 0);
        }
      }
    }
    __syncthreads();
  }

  // ---- epilogue: row sum is lane-local + partner half; normalize and store
  float lrow = lsum + __shfl_xor(lsum, 32);
  float li = 1.0f / lrow;
  const int s = qrow0 + l31;
#pragma unroll
  for (int db = 0; db < 4; ++db)
#pragma unroll
    for (int r = 0; r < 16; ++r) {
      int d = db * 32 + (r & 3) + 8 * (r >> 2) + 4 * hi;
      Op[(size_t)((b * 16 + h2) * 128 + d) * SEQ + s] = f2bf(oacc[db][r] * li);
    }
}

// ---------------------------------------------------------------------------
__global__ __launch_bounds__(256) void combine_kernel(
    const ushort_t* __restrict__ Op, const float* __restrict__ lq1,
    const float* __restrict__ lk1, const float* __restrict__ lq2,
    const float* __restrict__ lk2, ushort_t* __restrict__ Oc) {
  const int tid = threadIdx.x;
  const int st = blockIdx.x, h = blockIdx.y, b = blockIdx.z;
  float d1 = 0.f, d2 = 0.f;
  for (int i = 0; i < 64; ++i) { d1 += lq1[i] * lk1[i]; d2 += lq2[i] * lk2[i]; }
  const float lam = __expf(d1) - __expf(d2) + LAMBDA_INIT;

  const int sl = tid & 63, dg = tid >> 6;
  const int s = st * 64 + sl;
  const ushort_t* O1 = Op + (size_t)((b * 16 + 2 * h) * 128 + dg * 32) * SEQ + s;
  const ushort_t* O2 = O1 + (size_t)128 * SEQ;

  float u[32];
  float ssq = 0.f;
#pragma unroll
  for (int i = 0; i < 32; ++i) {
    float a = bf2f(O1[(size_t)i * SEQ]);
    float c = bf2f(O2[(size_t)i * SEQ]);
    float uu = a - lam * c;
    u[i] = uu;
    ssq += uu * uu;
  }
  __shared__ float red[4][64];
  red[dg][sl] = ssq;
  __syncthreads();
  float tot = red[0][sl] + red[1][sl] + red[2][sl] + red[3][sl];
  float scl = rsqrtf(tot * (1.0f / 128.0f) + 1e-5f) * (1.0f - LAMBDA_INIT);

  uint4v ow[4];
#pragma unroll
  for (int w = 0; w < 4; ++w)
#pragma unroll
    for (int j = 0; j < 4; ++j) {
      int i = w * 8 + j * 2;
      ow[w][j] = (unsigned int)f2bf(u[i] * scl) | ((unsigned int)f2bf(u[i + 1] * scl) << 16);
    }
  uint4v* dst = (uint4v*)&Oc[(size_t)(b * SEQ + s) * DIMM + h * 128 + dg * 32];
#pragma unroll
  for (int w = 0; w < 4; ++w) dst[w] = ow[w];
}

// ---------------------------------------------------------------------------
extern "C" void kernel_launch(void* const* d_in, const int* in_sizes, int n_in,
                              void* d_out, int out_size, void* d_ws, size_t ws_size,
                              hipStream_t stream) {
  const float* x   = (const float*)d_in[0];
  const float* Wq  = (const float*)d_in[1];
  const float* Wk  = (const float*)d_in[2];
  const float* Wv  = (const float*)d_in[3];
  const float* Wo  = (const float*)d_in[4];
  const float* lq1 = (const float*)d_in[5];
  const float* lk1 = (const float*)d_in[6];
  const float* lq2 = (const float*)d_in[7];
  const float* lk2 = (const float*)d_in[8];

  char* ws = (char*)d_ws;
  const size_t MB = 1 << 20;
  if (ws_size < 56 * MB) return;

  ushort_t* xb  = (ushort_t*)(ws + 0);
  ushort_t* Wqb = (ushort_t*)(ws + 8 * MB);
  ushort_t* Wkb = (ushort_t*)(ws + 10 * MB);
  ushort_t* Wvb = (ushort_t*)(ws + 12 * MB);
  ushort_t* Wob = (ushort_t*)(ws + 14 * MB);
  ushort_t* Qb  = (ushort_t*)(ws + 16 * MB);
  ushort_t* Kb  = (ushort_t*)(ws + 24 * MB);
  ushort_t* Vb  = (ushort_t*)(ws + 32 * MB);
  ushort_t* Opb = (ushort_t*)(ws + 40 * MB);
  ushort_t* Oc  = (ushort_t*)(ws + 0);   // reuses xb (dead after QKV gemm)

  cvt_all_kernel<<<8192, 256, 0, stream>>>(x, Wq, Wk, Wv, Wo, xb, Wqb, Wkb, Wvb, Wob);

  gemm_qkv_kernel<<<dim3(24, 32), 256, 0, stream>>>(xb, Wqb, Wkb, Wvb, Qb, Kb, Vb);

  attn_kernel<<<512, 256, 0, stream>>>(Qb, Kb, Vb, Opb);

  combine_kernel<<<dim3(32, 8, 2), 256, 0, stream>>>(Opb, lq1, lk1, lq2, lk2, Oc);

  gemm_bt64_kernel<<<dim3(16, 32), 256, 0, stream>>>(Oc, Wob, (float*)d_out, 4096, 1024, 1024);
}